// Round 7
// baseline (143.970 us; speedup 1.0000x reference)
//
#include <hip/hip_runtime.h>
#include <hip/hip_bf16.h>
#include <stdint.h>
#include <stddef.h>

#define L_LEN 4096
#define CIN   128
#define COUT  128
#define NB    32
#define KTOT  384            // 3 * CIN, kappa = k*128 + i
#define TN    64             // h-tile per pipeline step
#define TPB   8              // tiles marched per block
#define ROWS  (TN + 2)       // 66 (halo of 1 on each side)

typedef __bf16 bf16x8 __attribute__((ext_vector_type(8)));
typedef float  f32x4  __attribute__((ext_vector_type(4)));

__device__ __forceinline__ uint16_t f2bf(float f) {
    union { float f; uint32_t u; } v; v.f = f;
    return (uint16_t)((v.u + 0x7fffu + ((v.u >> 16) & 1u)) >> 16);  // RNE
}
__device__ __forceinline__ uint32_t pack2(float lo, float hi) {
    return (uint32_t)f2bf(lo) | ((uint32_t)f2bf(hi) << 16);
}

// async global->LDS, 16B per lane (dest = uniform base + lane*16)
__device__ __forceinline__ void gll16(const void* g, void* l) {
    __builtin_amdgcn_global_load_lds(
        (const __attribute__((address_space(1))) void*)g,
        (__attribute__((address_space(3))) void*)l, 16, 0, 0);
}

// barrier WITHOUT vmcnt drain: LDS visibility only. Staged global loads
// and epilogue stores stay in flight across it (T3/T4 mechanism).
#define BARRIER_NODRAIN() \
    asm volatile("s_waitcnt lgkmcnt(0)\n\ts_barrier" ::: "memory")

// ---- Prologue: combined bf16 weights in MFMA-FRAGMENT order + cbias ----
// Wc index = (((b*4 + og32)*12 + t)*2 + mt)*512 + lane*8 + j
//   o   = og32*32 + mt*16 + (lane&15)
//   col = t*32 + (lane>>4)*8 + j        (col = k*128 + i)
__global__ __launch_bounds__(256) void geps_combine(
    const float* __restrict__ codes, const float* __restrict__ weight,
    const float* __restrict__ Amat,  const float* __restrict__ Bmat,
    const float* __restrict__ bias,  const float* __restrict__ bias_ctx,
    uint16_t* __restrict__ Wc, float* __restrict__ cbias)
{
    int tid = blockIdx.x * 256 + threadIdx.x;
    if (tid < NB * COUT * KTOT) {
        int j    = tid & 7;
        int lane = (tid >> 3) & 63;
        int mt   = (tid >> 9) & 1;
        int tmp  = tid >> 10;
        int t    = tmp % 12;
        int bo   = tmp / 12;          // b*4 + og32
        int og   = bo & 3;
        int b    = bo >> 2;
        int col  = t * 32 + (lane >> 4) * 8 + j;   // kappa = k*128 + i
        int k    = col >> 7;
        int i    = col & 127;
        int o    = og * 32 + mt * 16 + (lane & 15);
        float cw = 0.f;
        #pragma unroll
        for (int c = 0; c < 2; ++c) {
            float a = Amat[i * 6 + c * 3 + k];
            #pragma unroll
            for (int r = 0; r < 2; ++r)
                cw += a * codes[b * 4 + c * 2 + r] * Bmat[o * 6 + r * 3 + k];
        }
        float val = weight[o * 384 + i * 3 + k] + cw;   // FACTOR = 1
        Wc[tid] = f2bf(val);
    }
    if (tid < NB * COUT) {
        int b = tid >> 7, o = tid & 127;
        float cb = bias[o];
        #pragma unroll
        for (int c = 0; c < 2; ++c)
            cb += codes[b * 4 + c * 2 + c] * bias_ctx[c * 128 + o];
        cbias[tid] = cb;
    }
}

// Macro hygiene: macro-locals L_/P_-prefixed (round-3 lesson).

// --- Stage HALF of a tile (64 i-rows x 64 h) into st[IT] (issue only).
#define LOAD_HALF(IT, H0)                                                    \
    {                                                                        \
        int L_p4 = ((IT) << 4) + (tid >> 4);                                 \
        int L_qd = tid & 15;                                                 \
        const float* L_r0 = inb + (size_t)(4 * L_p4) * L_LEN + (H0) + 4 * L_qd; \
        st[IT][0] = *(const float4*)(L_r0);                                  \
        st[IT][1] = *(const float4*)(L_r0 + L_LEN);                          \
        st[IT][2] = *(const float4*)(L_r0 + 2 * L_LEN);                      \
        st[IT][3] = *(const float4*)(L_r0 + 3 * L_LEN);                      \
        if ((IT) && tid < 128) {                                             \
            int L_p    = tid & 63;                                           \
            int L_side = tid >> 6;                                           \
            int L_r    = L_side ? (ROWS - 1) : 0;                            \
            int L_gh   = ((H0) - 1 + L_r) & (L_LEN - 1);                     \
            hx0 = inb[(size_t)(2 * L_p) * L_LEN + L_gh];                     \
            hx1 = inb[(size_t)(2 * L_p + 1) * L_LEN + L_gh];                 \
        }                                                                    \
    }

// --- Convert st[IT] to bf16, write swizzled LDS half (vmcnt wait implicit;
// in steady state the loads were issued a whole K-loop earlier -> free).
#define PACK_HALF(IT, XP)                                                    \
    {                                                                        \
        uint16_t* P_Xw = (XP);                                               \
        int P_p4 = ((IT) << 4) + (tid >> 4);                                 \
        int P_qd = tid & 15;                                                 \
        const int P_off = (4 * P_p4) & 7;                                    \
        const int P_pc  = P_p4 >> 1;                                         \
        _Pragma("unroll")                                                    \
        for (int P_j4 = 0; P_j4 < 4; ++P_j4) {                               \
            int P_r  = 1 + 4 * P_qd + P_j4;                                  \
            int P_ch = P_pc ^ (P_r & 15);                                    \
            uint2 P_w;                                                       \
            P_w.x = pack2(((const float*)&st[IT][0])[P_j4],                  \
                          ((const float*)&st[IT][1])[P_j4]);                 \
            P_w.y = pack2(((const float*)&st[IT][2])[P_j4],                  \
                          ((const float*)&st[IT][3])[P_j4]);                 \
            *(uint2*)&P_Xw[P_r * 128 + (P_ch << 3) + P_off] = P_w;           \
        }                                                                    \
        if ((IT) && tid < 128) {                                             \
            int P_p     = tid & 63;                                          \
            int P_side  = tid >> 6;                                          \
            int P_hr    = P_side ? (ROWS - 1) : 0;                           \
            int P_chunk = (P_p >> 2) ^ (P_hr & 15);                          \
            *(uint32_t*)&P_Xw[P_hr * 128 + (P_chunk << 3) + ((2 * P_p) & 7)] = \
                pack2(hx0, hx1);                                             \
        }                                                                    \
    }

// ---- Main: per-batch GEMM, M=o(128) x N=h x K=384, bf16 MFMA ----
// Round-7 design: drain-free marching pipeline.
//  * A-panel (96KB, all 4 waves) DMA'd to LDS once via global_load_lds ->
//    the K-loop has ZERO VMEM ops; its only waits are lgkm (ds_read->MFMA).
//  * Per tile: issue stage loads -> K-loop -> pack -> stores -> raw
//    s_barrier with lgkmcnt(0) ONLY. No vmcnt drain anywhere in the loop:
//    stage loads ride under the K-loop, stores ride under the next tile.
//    (rounds 2-6: __syncthreads = vmcnt(0) drain per tile exposed a full
//    HBM round-trip per tile regardless of occupancy -> 42us invariant.)
//  * Grid 256 = 1 block/CU, TPB=8 tiles marched; prologue drain paid once.
//  * XCD decode: 4 b's per XCD -> Wc slices + input L2-resident.
__global__ __launch_bounds__(256, 2) void geps_conv(
    const float* __restrict__ in, const uint16_t* __restrict__ Wc,
    const float* __restrict__ cbias, float* __restrict__ out)
{
    // A-panel, fragment-ordered: ALds[((wid*12 + t)*2 + mt)*512 + lane*8 + j]
    __shared__ uint16_t __attribute__((aligned(16))) ALds[4 * 12 * 1024];
    // Xt: element (r,i) at r*128 + (((i>>3)^(r&15))<<3) + (i&7)
    __shared__ uint16_t __attribute__((aligned(16))) Xt[2][ROWS * 128];
    __shared__ float cb[COUT];

    const int tid  = threadIdx.x;
    const int d    = blockIdx.x;         // 0..255
    const int xcd  = d & 7;
    const int b    = 4 * xcd + ((d >> 3) & 3);
    const int hb   = (d >> 5) * (TN * TPB);
    const int lane = tid & 63;
    const int wid  = tid >> 6;
    const int m16  = lane & 15;
    const int q    = lane >> 4;
    const int mq   = wid * 32;           // wave's o-offset (4 waves x 32 o)

    const float* inb = in + (size_t)b * CIN * L_LEN;

    float4 st[2][4];
    float  hx0 = 0.f, hx1 = 0.f;

    // --- prologue: stage tile 0 + DMA the A-panel + cbias ---
    LOAD_HALF(0, hb)
    LOAD_HALF(1, hb)
    {   // wave wid's 24KB panel: 24 x 1KB global_load_lds (pure DMA, 0 regs)
        const uint16_t* gsrc = Wc + (size_t)(b * 4 + wid) * 12288 + lane * 8;
        uint16_t* ldst = &ALds[wid * 12288];
        #pragma unroll
        for (int n = 0; n < 24; ++n)
            gll16(gsrc + n * 512, ldst + n * 512);
    }
    if (tid < COUT) cb[tid] = cbias[b * COUT + tid];
    PACK_HALF(0, &Xt[0][0])
    PACK_HALF(1, &Xt[0][0])
    __syncthreads();                     // the ONLY full drain (A + tile 0)

    f32x4 acc[2][4];
    int cur = 0;

    #pragma unroll 1
    for (int j = 0; j < TPB; ++j) {
        const int h0  = hb + j * TN;
        const bool pre = (j + 1 < TPB);

        // issue next tile's loads NOW; they land during the K-loop below
        if (pre) { LOAD_HALF(0, h0 + TN) LOAD_HALF(1, h0 + TN) }
        asm volatile("" ::: "memory");   // pin load-issue above the K-loop

        #pragma unroll
        for (int a = 0; a < 2; ++a)
            #pragma unroll
            for (int cc = 0; cc < 4; ++cc) acc[a][cc] = 0.0f;

        const uint16_t* Xc = &Xt[cur][0];
        const uint16_t* Aw = &ALds[wid * 12288 + lane * 8];

        #pragma unroll
        for (int t = 0; t < 12; ++t) {
            bf16x8 a0 = *(const bf16x8*)(Aw + t * 1024);
            bf16x8 a1 = *(const bf16x8*)(Aw + t * 1024 + 512);
            const int k   = t >> 2;      // kernel tap of this K-step
            const int i0c = (t & 3) << 2;
            bf16x8 bfv[4];
            #pragma unroll
            for (int nt = 0; nt < 4; ++nt) {
                int r  = nt * 16 + m16 + k;      // Xt row = h_local + k
                int ch = (i0c + q) ^ (r & 15);
                bfv[nt] = *(const bf16x8*)&Xc[r * 128 + (ch << 3)];
            }
            #pragma unroll
            for (int nt = 0; nt < 4; ++nt) {
                acc[0][nt] = __builtin_amdgcn_mfma_f32_16x16x32_bf16(
                    a0, bfv[nt], acc[0][nt], 0, 0, 0);
                acc[1][nt] = __builtin_amdgcn_mfma_f32_16x16x32_bf16(
                    a1, bfv[nt], acc[1][nt], 0, 0, 0);
            }
        }

        // pack next tile into the other buffer (waits only its own loads,
        // issued one full K-loop ago)
        if (pre) { PACK_HALF(0, &Xt[cur ^ 1][0]) PACK_HALF(1, &Xt[cur ^ 1][0]) }

        // --- epilogue stores: issued LAST (newest in vmcnt FIFO, never
        // waited on; they drain under the next tile's K-loop) ---
        float* outb = out + (size_t)b * COUT * L_LEN + h0;
        #pragma unroll
        for (int mt = 0; mt < 2; ++mt) {
            #pragma unroll
            for (int reg = 0; reg < 4; ++reg) {
                int o = mq + mt * 16 + q * 4 + reg;
                float bv = cb[o];
                float* orow = outb + (size_t)o * L_LEN;
                #pragma unroll
                for (int nt = 0; nt < 4; ++nt)
                    __builtin_nontemporal_store(acc[mt][nt][reg] + bv,
                                                &orow[nt * 16 + m16]);
            }
        }

        BARRIER_NODRAIN();               // LDS visibility only; no vmcnt
        cur ^= 1;
    }
}

extern "C" void kernel_launch(void* const* d_in, const int* in_sizes, int n_in,
                              void* d_out, int out_size, void* d_ws, size_t ws_size,
                              hipStream_t stream) {
    const float* input    = (const float*)d_in[0];
    const float* codes    = (const float*)d_in[1];
    const float* weight   = (const float*)d_in[2];
    const float* Amat     = (const float*)d_in[3];
    const float* Bmat     = (const float*)d_in[4];
    const float* bias     = (const float*)d_in[5];
    const float* bias_ctx = (const float*)d_in[6];
    float* out = (float*)d_out;

    uint16_t* Wc    = (uint16_t*)d_ws;
    float*    cbias = (float*)((char*)d_ws + (size_t)NB * COUT * KTOT * 2);

    geps_combine<<<dim3((NB * COUT * KTOT) / 256), 256, 0, stream>>>(
        codes, weight, Amat, Bmat, bias, bias_ctx, Wc, cbias);
    // 32 b x 8 h-groups = 256 blocks = 1/CU, each marching 8 tiles
    geps_conv<<<dim3(NB * (L_LEN / (TN * TPB))), 256, 0, stream>>>(
        input, Wc, cbias, out);
}

// Round 8
// 128.279 us; speedup vs baseline: 1.1223x; 1.1223x over previous
//
#include <hip/hip_runtime.h>
#include <hip/hip_bf16.h>
#include <stdint.h>
#include <stddef.h>

#define L_LEN 4096
#define CIN   128
#define COUT  128
#define NB    32
#define KTOT  384            // 3 * CIN, kappa = k*128 + i
#define TN    256            // h-tile per block (4 x 64h sub-tiles)
#define ROWS  (TN + 2)       // 258 (halo of 1 on each side)

typedef __bf16 bf16x8 __attribute__((ext_vector_type(8)));
typedef float  f32x4  __attribute__((ext_vector_type(4)));

__device__ __forceinline__ uint16_t f2bf(float f) {
    union { float f; uint32_t u; } v; v.f = f;
    return (uint16_t)((v.u + 0x7fffu + ((v.u >> 16) & 1u)) >> 16);  // RNE
}
__device__ __forceinline__ uint32_t pack2(float lo, float hi) {
    return (uint32_t)f2bf(lo) | ((uint32_t)f2bf(hi) << 16);
}

// ---- Prologue: combined bf16 weights in MFMA-FRAGMENT order + cbias ----
// Wc index = (((b*4 + og32)*12 + t)*2 + mt)*512 + lane*8 + j
//   o   = og32*32 + mt*16 + (lane&15)
//   col = t*32 + (lane>>4)*8 + j        (col = k*128 + i)
__global__ __launch_bounds__(256) void geps_combine(
    const float* __restrict__ codes, const float* __restrict__ weight,
    const float* __restrict__ Amat,  const float* __restrict__ Bmat,
    const float* __restrict__ bias,  const float* __restrict__ bias_ctx,
    uint16_t* __restrict__ Wc, float* __restrict__ cbias)
{
    int tid = blockIdx.x * 256 + threadIdx.x;
    if (tid < NB * COUT * KTOT) {
        int j    = tid & 7;
        int lane = (tid >> 3) & 63;
        int mt   = (tid >> 9) & 1;
        int tmp  = tid >> 10;
        int t    = tmp % 12;
        int bo   = tmp / 12;          // b*4 + og32
        int og   = bo & 3;
        int b    = bo >> 2;
        int col  = t * 32 + (lane >> 4) * 8 + j;   // kappa = k*128 + i
        int k    = col >> 7;
        int i    = col & 127;
        int o    = og * 32 + mt * 16 + (lane & 15);
        float cw = 0.f;
        #pragma unroll
        for (int c = 0; c < 2; ++c) {
            float a = Amat[i * 6 + c * 3 + k];
            #pragma unroll
            for (int r = 0; r < 2; ++r)
                cw += a * codes[b * 4 + c * 2 + r] * Bmat[o * 6 + r * 3 + k];
        }
        float val = weight[o * 384 + i * 3 + k] + cw;   // FACTOR = 1
        Wc[tid] = f2bf(val);
    }
    if (tid < NB * COUT) {
        int b = tid >> 7, o = tid & 127;
        float cb = bias[o];
        #pragma unroll
        for (int c = 0; c < 2; ++c)
            cb += codes[b * 4 + c * 2 + c] * bias_ctx[c * 128 + o];
        cbias[tid] = cb;
    }
}

// Macro hygiene: macro-locals L_/P_-prefixed, unique (round-3 lesson).

// --- Stage chunk C = ihalf*4 + w: 64 i-rows (ihalf) x 64 h (window w).
// KEY (round-8): w is the INNER sequence -> each i-row is read as 4
// back-to-back 256B runs = 1KB effectively-sequential per row, instead of
// one isolated 256B run (the HBM access-granularity fix).
#define LOADC(C, SB)                                                         \
    {                                                                        \
        int L_p4 = ((C) >> 2) * 16 + (tid >> 4);                             \
        int L_qd = tid & 15;                                                 \
        const float* L_r0 = inb + (size_t)(4 * L_p4) * L_LEN + h0 +          \
                            ((C) & 3) * 64 + 4 * L_qd;                       \
        (SB)[0] = *(const float4*)(L_r0);                                    \
        (SB)[1] = *(const float4*)(L_r0 + L_LEN);                            \
        (SB)[2] = *(const float4*)(L_r0 + 2 * L_LEN);                        \
        (SB)[3] = *(const float4*)(L_r0 + 3 * L_LEN);                        \
    }

// --- Convert chunk C regs to bf16, write swizzled LDS.
// Xt element (r,i) at r*128 + (((i>>3)^(r&15))<<3) + (i&7).
#define PACKC(C, SB)                                                         \
    {                                                                        \
        int P_p4 = ((C) >> 2) * 16 + (tid >> 4);                             \
        int P_qd = tid & 15;                                                 \
        const int P_off = (4 * P_p4) & 7;                                    \
        const int P_pc  = P_p4 >> 1;                                         \
        _Pragma("unroll")                                                    \
        for (int P_j4 = 0; P_j4 < 4; ++P_j4) {                               \
            int P_r  = 1 + ((C) & 3) * 64 + 4 * P_qd + P_j4;                 \
            int P_ch = P_pc ^ (P_r & 15);                                    \
            uint2 P_w;                                                       \
            P_w.x = pack2(((const float*)&(SB)[0])[P_j4],                    \
                          ((const float*)&(SB)[1])[P_j4]);                   \
            P_w.y = pack2(((const float*)&(SB)[2])[P_j4],                    \
                          ((const float*)&(SB)[3])[P_j4]);                   \
            *(uint2*)&Xt[P_r * 128 + (P_ch << 3) + P_off] = P_w;             \
        }                                                                    \
    }

// ---- Main: per-batch GEMM, M=o(128) x N=h(256/block) x K=384, bf16 MFMA.
// Round-8 theory: the 42us invariant across 7 structures = HBM access
// granularity (256-512B strided reads, 64B nontemporal writes), NOT
// scheduling. Fixes: (1) 1KB-sequential-per-row staged reads (w-inner
// order); (2) PLAIN cached stores (out fits 256MB L3; L2/L3 merges the
// 64B fragments -> big writebacks). NT stores (rounds 1-7) bypassed L2
// merge and went to HBM in 64B granules.
// Structure = round-0-simple: stage -> one barrier -> 4 barrier-free
// sub-tile K-loops + stores -> exit. 512 blocks (2/CU), XCD-pinned b
// (Wc + input slices L2-resident, verified rounds 5/6), rolling L2
// A-stream (spill-free, verified rounds 5-6).
__global__ __launch_bounds__(256, 2) void geps_conv(
    const float* __restrict__ in, const uint16_t* __restrict__ Wc,
    const float* __restrict__ cbias, float* __restrict__ out)
{
    __shared__ uint16_t __attribute__((aligned(16))) Xt[ROWS * 128]; // 66KB
    __shared__ float cb[COUT];

    const int tid  = threadIdx.x;
    const int d    = blockIdx.x;         // 0..511
    const int xcd  = d & 7;
    const int b    = 4 * xcd + ((d >> 3) & 3);
    const int h0   = (d >> 5) * TN;      // 16 h-groups
    const int lane = tid & 63;
    const int wid  = tid >> 6;
    const int m16  = lane & 15;
    const int q    = lane >> 4;
    const int mq   = wid * 32;           // wave's o-offset (4 waves x 32 o)

    const float* inb = in + (size_t)b * CIN * L_LEN;
    // A-fragment stream base for this (b, wave): 12 steps x 2 mt x 512 bf16
    const uint16_t* WcW = Wc + (size_t)(b * 4 + wid) * 12288 + lane * 8;

    if (tid < COUT) cb[tid] = cbias[b * COUT + tid];

    // --- halo columns r=0 (h0-1) and r=257 (h0+256): issue earliest ---
    float hx0, hx1;
    {
        int L_p    = tid & 63;
        int L_side = (tid >> 6) & 1;     // waves 0,2: left; 1,3: right
        int L_r    = L_side ? (ROWS - 1) : 0;
        int L_gh   = (h0 - 1 + L_r) & (L_LEN - 1);
        hx0 = inb[(size_t)(2 * L_p) * L_LEN + L_gh];
        hx1 = inb[(size_t)(2 * L_p + 1) * L_LEN + L_gh];
    }

    // --- stage: 8 chunks, 2-deep rolling regs; vmcnt waits are per-chunk
    // (pack c waits loads c while loads c+1 stay in flight) ---
    float4 st[2][4];
    LOADC(0, st[0])
    #pragma unroll
    for (int c = 0; c < 8; ++c) {
        if (c < 7) LOADC(c + 1, st[(c + 1) & 1])
        asm volatile("" ::: "memory");   // keep next-chunk issue above pack
        PACKC(c, st[c & 1])
    }
    if (tid < 128) {                     // halo pack (loads long since done)
        int P_p     = tid & 63;
        int P_side  = tid >> 6;
        int P_hr    = P_side ? (ROWS - 1) : 0;
        int P_chunk = (P_p >> 2) ^ (P_hr & 15);
        *(uint32_t*)&Xt[P_hr * 128 + (P_chunk << 3) + ((2 * P_p) & 7)] =
            pack2(hx0, hx1);
    }

    __syncthreads();                     // the only barrier

    // --- compute: 4 sub-tiles, no barriers (Xt read-only), stores ride ---
    #pragma unroll 1
    for (int s = 0; s < 4; ++s) {
        f32x4 acc[2][4];
        #pragma unroll
        for (int a = 0; a < 2; ++a)
            #pragma unroll
            for (int cc = 0; cc < 4; ++cc) acc[a][cc] = 0.0f;

        // rolling A-fragment stream (L2-resident Wc), prefetch distance 2
        bf16x8 ar[3][2];
        ar[0][0] = *(const bf16x8*)(WcW);
        ar[0][1] = *(const bf16x8*)(WcW + 512);
        ar[1][0] = *(const bf16x8*)(WcW + 1024);
        ar[1][1] = *(const bf16x8*)(WcW + 1536);

        #pragma unroll
        for (int t = 0; t < 12; ++t) {
            if (t + 2 < 12) {
                ar[(t + 2) % 3][0] = *(const bf16x8*)(WcW + (t + 2) * 1024);
                ar[(t + 2) % 3][1] = *(const bf16x8*)(WcW + (t + 2) * 1024 + 512);
            }
            const int k   = t >> 2;      // kernel tap of this K-step
            const int i0c = (t & 3) << 2;
            bf16x8 bfv[4];
            #pragma unroll
            for (int nt = 0; nt < 4; ++nt) {
                int r  = s * 64 + nt * 16 + m16 + k;   // Xt row = h_local + k
                int ch = (i0c + q) ^ (r & 15);
                bfv[nt] = *(const bf16x8*)&Xt[r * 128 + (ch << 3)];
            }
            #pragma unroll
            for (int nt = 0; nt < 4; ++nt) {
                acc[0][nt] = __builtin_amdgcn_mfma_f32_16x16x32_bf16(
                    ar[t % 3][0], bfv[nt], acc[0][nt], 0, 0, 0);
                acc[1][nt] = __builtin_amdgcn_mfma_f32_16x16x32_bf16(
                    ar[t % 3][1], bfv[nt], acc[1][nt], 0, 0, 0);
            }
        }

        // --- sub-tile stores: PLAIN (cached) -> L2/L3 write-merge.
        // C/D layout col=lane&15 (h), row=(lane>>4)*4+reg (o).
        float* outb = out + (size_t)b * COUT * L_LEN + h0 + s * 64;
        #pragma unroll
        for (int mt = 0; mt < 2; ++mt) {
            #pragma unroll
            for (int reg = 0; reg < 4; ++reg) {
                int o = mq + mt * 16 + q * 4 + reg;
                float bv = cb[o];
                float* orow = outb + (size_t)o * L_LEN;
                #pragma unroll
                for (int nt = 0; nt < 4; ++nt)
                    orow[nt * 16 + m16] = acc[mt][nt][reg] + bv;
            }
        }
    }
}

extern "C" void kernel_launch(void* const* d_in, const int* in_sizes, int n_in,
                              void* d_out, int out_size, void* d_ws, size_t ws_size,
                              hipStream_t stream) {
    const float* input    = (const float*)d_in[0];
    const float* codes    = (const float*)d_in[1];
    const float* weight   = (const float*)d_in[2];
    const float* Amat     = (const float*)d_in[3];
    const float* Bmat     = (const float*)d_in[4];
    const float* bias     = (const float*)d_in[5];
    const float* bias_ctx = (const float*)d_in[6];
    float* out = (float*)d_out;

    uint16_t* Wc    = (uint16_t*)d_ws;
    float*    cbias = (float*)((char*)d_ws + (size_t)NB * COUT * KTOT * 2);

    geps_combine<<<dim3((NB * COUT * KTOT) / 256), 256, 0, stream>>>(
        codes, weight, Amat, Bmat, bias, bias_ctx, Wc, cbias);
    // 32 b x 16 h-groups = 512 blocks = 2/CU
    geps_conv<<<dim3(NB * (L_LEN / TN)), 256, 0, stream>>>(
        input, Wc, cbias, out);
}